// Round 3
// baseline (145.692 us; speedup 1.0000x reference)
//
#include <hip/hip_runtime.h>
#include <hip/hip_bf16.h>
#include <hip/hip_fp16.h>

#define NB 16
#define CCH 64
#define LL 4096   // 64*64
#define DD 1024   // 32*32

typedef _Float16 h8 __attribute__((ext_vector_type(8)));
typedef _Float16 h4 __attribute__((ext_vector_type(4)));
typedef _Float16 h2 __attribute__((ext_vector_type(2)));
typedef float    f4v __attribute__((ext_vector_type(4)));

#if defined(__has_builtin)
#if __has_builtin(__builtin_amdgcn_exp2f)
#define EXP2F(x) __builtin_amdgcn_exp2f(x)
#endif
#endif
#ifndef EXP2F
#define EXP2F(x) exp2f(x)
#endif

#define MFMA16(a, b, c) __builtin_amdgcn_mfma_f32_16x16x32_f16((a), (b), (c), 0, 0, 0)

// ---------------------------------------------------------------------------
// Kernel 1: MFMA-GEMM prep (exact R9 version — best measured ~18 µs).
// out[px][o] = sum_c x[c][px] * wall[o][c]; o: 0-7 theta (log2e-scaled),
// 8-15 phi, 16-47 g. Block = 4 waves = 64-px tile; grid = N*64 = 1024.
// ---------------------------------------------------------------------------
__global__ __launch_bounds__(256, 6) void prep_kernel(
    const float* __restrict__ x,        // [N, 64, 4096]
    const float* __restrict__ w_theta,  // [8, 64]
    const float* __restrict__ w_phi,    // [8, 64]
    const float* __restrict__ w_g,      // [32, 64]
    _Float16* __restrict__ theta_out,   // [N, 4096, 8]  (pre-scaled by log2e)
    _Float16* __restrict__ phi_out,     // [N, 1024, 8]
    _Float16* __restrict__ gT_out)      // [N, 32, 1024]
{
    __shared__ __align__(16) float smem[64 * 68];   // 17.4 KB
    float* xs   = smem;        // [64 ch][68] f32 (px stride 68)
    float* pool = smem;        // [64 px][49] f32 (aliases xs after barrier)

    const int n    = blockIdx.x >> 6;
    const int rem  = blockIdx.x & 63;
    const int rg   = rem >> 1;          // row-pair 0..31 (rows 2rg, 2rg+1)
    const int half = rem & 1;           // column half (32 cols)
    const int tid  = threadIdx.x;
    const int w    = tid >> 6;          // wave = M-tile 0..3
    const int lane = tid & 63;
    const int m16  = lane & 15;
    const int quad = lane >> 4;

    // ---- B-frags from weights: B[k = kc*32 + quad*8 + j][o = t*16 + m16]
    h8 bf[3][2];
#pragma unroll
    for (int t = 0; t < 3; ++t) {
        const float* row;
        float scale = 1.0f;
        if (t == 0) {
            if (m16 < 8) { row = w_theta + m16 * 64; scale = 1.44269504f; }
            else         { row = w_phi + (m16 - 8) * 64; }
        } else if (t == 1) {
            row = w_g + m16 * 64;
        } else {
            row = w_g + (16 + m16) * 64;
        }
#pragma unroll
        for (int kc = 0; kc < 2; ++kc) {
            const float* p = row + kc * 32 + quad * 8;
            float4 a = *(const float4*)p;
            float4 b = *(const float4*)(p + 4);
            bf[t][kc][0] = (_Float16)(a.x * scale);
            bf[t][kc][1] = (_Float16)(a.y * scale);
            bf[t][kc][2] = (_Float16)(a.z * scale);
            bf[t][kc][3] = (_Float16)(a.w * scale);
            bf[t][kc][4] = (_Float16)(b.x * scale);
            bf[t][kc][5] = (_Float16)(b.y * scale);
            bf[t][kc][6] = (_Float16)(b.z * scale);
            bf[t][kc][7] = (_Float16)(b.w * scale);
        }
    }

    // ---- stage x tile: 64 ch x 64 px, float4 loads -> ds_write_b128 ----
    {
        const int ch = tid >> 2;
        const int s  = tid & 3;
        const float* xc = x + (size_t)n * CCH * LL + (size_t)ch * LL;
        float4 vv[4];
#pragma unroll
        for (int i = 0; i < 4; ++i) {
            const int f    = i * 4 + s;
            const int row  = f >> 3;
            const int colg = f & 7;
            const int l    = (rg * 2 + row) * 64 + half * 32 + colg * 4;
            vv[i] = *(const float4*)(xc + l);
        }
#pragma unroll
        for (int i = 0; i < 4; ++i) {
            const int f    = i * 4 + s;
            const int row  = f >> 3;
            const int colg = f & 7;
            *(float4*)(xs + ch * 68 + row * 32 + colg * 4) = vv[i];
        }
    }
    __syncthreads();

    // ---- A-frags: A[m = w*16 + m16][k = kc*32 + quad*8 + j] from xs ----
    h8 af[2];
#pragma unroll
    for (int kc = 0; kc < 2; ++kc) {
#pragma unroll
        for (int j = 0; j < 8; ++j) {
            float v = xs[(kc * 32 + quad * 8 + j) * 68 + w * 16 + m16];
            af[kc][j] = (_Float16)v;
        }
    }

    // ---- 6 MFMAs: 3 N-tiles x 2 K-chunks ----
    f4v cfr[3];
#pragma unroll
    for (int t = 0; t < 3; ++t) {
        f4v c = {0.f, 0.f, 0.f, 0.f};
        c = MFMA16(af[0], bf[t][0], c);
        c = MFMA16(af[1], bf[t][1], c);
        cfr[t] = c;
    }
    __syncthreads();   // all xs reads done -> pool may alias

    // ---- C -> pool[px][o]: D row = quad*4+r (px-local), col = m16
    {
#pragma unroll
        for (int t = 0; t < 3; ++t) {
#pragma unroll
            for (int r = 0; r < 4; ++r)
                pool[(w * 16 + quad * 4 + r) * 49 + t * 16 + m16] = cfr[t][r];
        }
    }
    __syncthreads();

    // ---- theta store: one thread per px, h8
    if (tid < 64) {
        const int px  = tid;
        const int row = px >> 5, col = px & 31;
        const int l   = (rg * 2 + row) * 64 + half * 32 + col;
        const float* pr = pool + px * 49;
        h8 tv;
#pragma unroll
        for (int k = 0; k < 8; ++k) tv[k] = (_Float16)pr[k];
        *(h8*)(theta_out + ((size_t)n * LL + l) * 8) = tv;
    }

    // ---- 2x2 maxpool: 16 pooled cols x 40 features
    const int d_base = rg * 32 + half * 16;
    for (int idx = tid; idx < 640; idx += 256) {
        const int f40 = idx >> 4;       // 0..7 phi, 8..39 g
        const int pc  = idx & 15;
        const int fcol = 8 + f40;
        float v = fmaxf(fmaxf(pool[(2 * pc) * 49 + fcol],      pool[(2 * pc + 1) * 49 + fcol]),
                        fmaxf(pool[(32 + 2 * pc) * 49 + fcol], pool[(33 + 2 * pc) * 49 + fcol]));
        const int d = d_base + pc;
        if (f40 < 8) phi_out[((size_t)n * DD + d) * 8 + f40] = (_Float16)v;
        else         gT_out[((size_t)n * 32 + (f40 - 8)) * DD + d] = (_Float16)v;
    }
}

// ---------------------------------------------------------------------------
// Kernel 2: attn, R13. Same verified math as R12 (MFMA QK^T with K=8 padded
// to 32; permuted gT k<->d map so S^T lands exactly in the PV A-frag), but
// resource-fixed: R12 at launch_bounds(256,8) spilled (WRITE_SIZE 61 MB vs
// 16 MB output) and was latency-bound (MfmaUtil 6%, unroll 2 = no ILP).
// R13: launch_bounds(256,4) (128-VGPR cap, no spill), ALL 32 gT b64 loads
// prefetched into registers before the staging barrier (one latency
// exposure), full unroll of the 8-chunk loop, wof loaded post-loop,
// ssum accumulators split 2-way to halve the serial fadd chain.
// ---------------------------------------------------------------------------
__global__ __launch_bounds__(256, 4) void attn_kernel(
    const float*    __restrict__ x,       // [N, 64, 4096]
    const _Float16* __restrict__ theta,   // [N, 4096, 8]
    const _Float16* __restrict__ phi,     // [N, 1024, 8]
    const _Float16* __restrict__ gT,      // [N, 32, 1024]
    const float*    __restrict__ w_o,     // [64, 32]
    const float*    __restrict__ gamma_p, // scalar
    float*          __restrict__ out)     // [N, 64, 4096]
{
    // phi_s: [1024][8] f16 = 16384 B (unpadded).
    // red [4][32][37] f32 = 18944 B aliases phi_s; ssum at +18944 (512 B);
    // out_s [32][68] f32 = 8704 B aliases red after the combine barrier.
    __shared__ __align__(16) char smem[18944 + 512];
    _Float16* phi_s  = (_Float16*)smem;
    float*    red    = (float*)smem;                // [4][32][37]
    float*    out_s  = (float*)smem;                // [32][68]
    float*    ssum_s = (float*)(smem + 18944);      // [4][32]

    const int n    = blockIdx.x >> 7;
    const int lblk = blockIdx.x & 127;
    const int tid  = threadIdx.x;
    const int h    = tid >> 6;            // D-quarter 0..3 (one per wave)
    const int lane = tid & 63;
    const int m16  = lane & 15;
    const int quad = lane >> 4;
    const int l0   = lblk * 32;           // block query base (32 q)

    const _Float16* gT_n = gT + (size_t)n * 32 * DD;

    // ---- prefetch ALL gT b-frags for this wave (16 x h8 = 64 VGPR;
    // statically indexed under full unroll -> stays in registers).
    // k<->d map: k = quad*8+j  <->  d = d0 + (j<4 ? quad*4+j : 16+quad*4+j-4)
    const _Float16* gq0 = gT_n + (size_t)m16 * DD + h * 256;        // ch-tile 0
    const _Float16* gq1 = gT_n + (size_t)(16 + m16) * DD + h * 256; // ch-tile 1
    h8 b0v[8], b1v[8];
#pragma unroll
    for (int c = 0; c < 8; ++c) {
        const int d0 = c * 32;
        h4 b0lo = *(const h4*)(gq0 + d0 + quad * 4);
        h4 b0hi = *(const h4*)(gq0 + d0 + 16 + quad * 4);
        h4 b1lo = *(const h4*)(gq1 + d0 + quad * 4);
        h4 b1hi = *(const h4*)(gq1 + d0 + 16 + quad * 4);
        b0v[c] = __builtin_shufflevector(b0lo, b0hi, 0, 1, 2, 3, 4, 5, 6, 7);
        b1v[c] = __builtin_shufflevector(b1lo, b1hi, 0, 1, 2, 3, 4, 5, 6, 7);
    }

    // ---- stage full phi[n] into LDS, plain layout [d][8]
    {
        const float4* ps = (const float4*)(phi + (size_t)n * DD * 8);
        float4* pd = (float4*)phi_s;
#pragma unroll
        for (int i = 0; i < 4; ++i) {
            const int d = tid + 256 * i;
            pd[d] = ps[d];
        }
    }

    // theta rows for this block's two 16-q M-tiles -> S^T B-frags
    // B[k=quad*8+j][n=q=m16] = theta[q][k]; real k<8 -> quad 0 only
    const h8 zero8 = {};
    h8 bq0 = zero8, bq1 = zero8;
    if (quad == 0) {
        bq0 = *(const h8*)(theta + ((size_t)n * LL + l0 + m16) * 8);
        bq1 = *(const h8*)(theta + ((size_t)n * LL + l0 + 16 + m16) * 8);
    }

    __syncthreads();   // phi_s ready

    f4v c00 = {0.f, 0.f, 0.f, 0.f}, c01 = c00, c10 = c00, c11 = c00;
    float ssum0a = 0.f, ssum0b = 0.f, ssum1a = 0.f, ssum1b = 0.f;

    const _Float16* ph_base = phi_s + (size_t)(h * 256 + m16) * 8;  // quad0 rows

#pragma unroll
    for (int c = 0; c < 8; ++c) {
        const int d0 = c * 32;

        // phi A-frags for d-tiles: A[m=d_local=m16][k=quad*8+j];
        // real k<8 -> only quad 0 loads, others stay zero.
        h8 ap0 = zero8, ap1 = zero8;
        if (quad == 0) {
            ap0 = *(const h8*)(ph_base + d0 * 8);
            ap1 = *(const h8*)(ph_base + (d0 + 16) * 8);
        }

        const f4v z4 = {0.f, 0.f, 0.f, 0.f};

        // ---- all 4 S-MFMAs back-to-back (pipeline the matrix unit)
        f4v s00 = MFMA16(ap0, bq0, z4);   // d-tile0 x q-tile0
        f4v s10 = MFMA16(ap1, bq0, z4);   // d-tile1 x q-tile0
        f4v s01 = MFMA16(ap0, bq1, z4);   // d-tile0 x q-tile1
        f4v s11 = MFMA16(ap1, bq1, z4);   // d-tile1 x q-tile1

        // ---- exp -> PV A-frags (theta pre-scaled by log2e)
        h8 a0, a1;
#pragma unroll
        for (int r = 0; r < 4; ++r) {
            float e0 = EXP2F(s00[r]); ssum0a += e0; a0[r]     = (_Float16)e0;
            float f0 = EXP2F(s10[r]); ssum0b += f0; a0[4 + r] = (_Float16)f0;
            float e1 = EXP2F(s01[r]); ssum1a += e1; a1[r]     = (_Float16)e1;
            float f1 = EXP2F(s11[r]); ssum1b += f1; a1[4 + r] = (_Float16)f1;
        }

        // ---- PV accumulate (prefetched B-frags)
        c00 = MFMA16(a0, b0v[c], c00);
        c01 = MFMA16(a0, b1v[c], c01);
        c10 = MFMA16(a1, b0v[c], c10);
        c11 = MFMA16(a1, b1v[c], c11);
    }

    float ssum0 = ssum0a + ssum0b;
    float ssum1 = ssum1a + ssum1b;

    // quarter-D softmax denominators (quads hold disjoint d)
    ssum0 += __shfl_xor(ssum0, 16); ssum0 += __shfl_xor(ssum0, 32);
    ssum1 += __shfl_xor(ssum1, 16); ssum1 += __shfl_xor(ssum1, 32);
    if (quad == 0) {
        ssum_s[h * 32 + m16]      = ssum0;   // beyond phi_s use: safe now
        ssum_s[h * 32 + 16 + m16] = ssum1;
    }
    __syncthreads();   // ALL waves done reading phi_s -> red may alias it

    // write partial C (C layout: row q = quad*4+r, col ch = m16) into red
    {
        float* rg = red + (size_t)h * 32 * 37;
#pragma unroll
        for (int r = 0; r < 4; ++r) {
            const int rr = quad * 4 + r;
            rg[rr * 37 + m16]             = c00[r];
            rg[rr * 37 + 16 + m16]        = c01[r];
            rg[(16 + rr) * 37 + m16]      = c10[r];
            rg[(16 + rr) * 37 + 16 + m16] = c11[r];
        }
    }
    __syncthreads();

    // w_o B-frags for this wave's och-pair: och = m16 + 16*(vp*2+i)
    // (loaded post-loop to keep the hot-loop register window small)
    const int vp = h >> 1;
    h8 wof[2];
#pragma unroll
    for (int i = 0; i < 2; ++i) {
        const float* wr = w_o + (size_t)(m16 + 16 * (vp * 2 + i)) * 32 + quad * 8;
        float4 wa = *(const float4*)wr;
        float4 wb = *(const float4*)(wr + 4);
        wof[i][0] = (_Float16)wa.x; wof[i][1] = (_Float16)wa.y;
        wof[i][2] = (_Float16)wa.z; wof[i][3] = (_Float16)wa.w;
        wof[i][4] = (_Float16)wb.x; wof[i][5] = (_Float16)wb.y;
        wof[i][6] = (_Float16)wb.z; wof[i][7] = (_Float16)wb.w;
    }

    // combine 4 quarters + normalize + pack A-frag.
    // wave h projects M-tile t = h&1: q = t*16 + m16, k = gch = quad*8+j
    const int t = h & 1;
    h8 pa;
    {
        const int q = t * 16 + m16;
        const float* rq = red + q * 37 + quad * 8;
        float ss = ssum_s[q] + ssum_s[32 + q] + ssum_s[64 + q] + ssum_s[96 + q];
        float inv = 1.0f / ss;
#pragma unroll
        for (int j = 0; j < 8; ++j) {
            float sv = rq[j] + rq[32 * 37 + j] + rq[64 * 37 + j] + rq[96 * 37 + j];
            pa[j] = (_Float16)(sv * inv);
        }
    }
    __syncthreads();   // everyone done reading red -> safe to alias out_s

    // projection: D[row = local q = quad*4+r][col = och], q = t*16 + quad*4+r
    const f4v zero = {0.f, 0.f, 0.f, 0.f};
#pragma unroll
    for (int i = 0; i < 2; ++i) {
        f4v pv = MFMA16(pa, wof[i], zero);
        const int och = m16 + 16 * (vp * 2 + i);
        float* od = out_s + (size_t)(t * 16 + quad * 4) * 68 + och;
#pragma unroll
        for (int r = 0; r < 4; ++r) od[r * 68] = pv[r];
    }
    __syncthreads();

    // coalesced store + residual: thread -> och = tid>>2, 8 q from (tid&3)*8
    const float gamma = gamma_p[0];
    const int soch = tid >> 2;
    const int qoff = (tid & 3) * 8;
    const float* xrow = x   + (size_t)n * CCH * LL + (size_t)soch * LL + l0 + qoff;
    float*       orow = out + (size_t)n * CCH * LL + (size_t)soch * LL + l0 + qoff;
#pragma unroll
    for (int i = 0; i < 2; ++i) {
        float4 xv = *(const float4*)(xrow + i * 4);
        float4 ov;
        ov.x = xv.x + gamma * out_s[(qoff + i * 4)     * 68 + soch];
        ov.y = xv.y + gamma * out_s[(qoff + i * 4 + 1) * 68 + soch];
        ov.z = xv.z + gamma * out_s[(qoff + i * 4 + 2) * 68 + soch];
        ov.w = xv.w + gamma * out_s[(qoff + i * 4 + 3) * 68 + soch];
        *(float4*)(orow + i * 4) = ov;
    }
}

// ---------------------------------------------------------------------------
extern "C" void kernel_launch(void* const* d_in, const int* in_sizes, int n_in,
                              void* d_out, int out_size, void* d_ws, size_t ws_size,
                              hipStream_t stream) {
    const float* x       = (const float*)d_in[0];
    const float* w_theta = (const float*)d_in[1];
    const float* w_phi   = (const float*)d_in[2];
    const float* w_g     = (const float*)d_in[3];
    const float* w_o     = (const float*)d_in[4];
    const float* gamma   = (const float*)d_in[5];
    float* out = (float*)d_out;

    // ws layout (f16): theta 1 MB | phi 256 KB | gT 1 MB
    _Float16* theta_h = (_Float16*)d_ws;                    // N*L*8
    _Float16* phi_h   = theta_h + (size_t)NB * LL * 8;      // N*D*8
    _Float16* gT_h    = phi_h   + (size_t)NB * DD * 8;      // N*32*D

    prep_kernel<<<1024, 256, 0, stream>>>(x, w_theta, w_phi, w_g,
                                          theta_h, phi_h, gT_h);
    attn_kernel<<<2048, 256, 0, stream>>>(x, theta_h, phi_h, gT_h,
                                          w_o, gamma, out);
}

// Round 4
// 140.623 us; speedup vs baseline: 1.0360x; 1.0360x over previous
//
#include <hip/hip_runtime.h>
#include <hip/hip_bf16.h>
#include <hip/hip_fp16.h>

#define NB 16
#define CCH 64
#define LL 4096   // 64*64
#define DD 1024   // 32*32

typedef _Float16 h8 __attribute__((ext_vector_type(8)));
typedef _Float16 h4 __attribute__((ext_vector_type(4)));
typedef _Float16 h2 __attribute__((ext_vector_type(2)));
typedef float    f4v __attribute__((ext_vector_type(4)));

#if defined(__has_builtin)
#if __has_builtin(__builtin_amdgcn_exp2f)
#define EXP2F(x) __builtin_amdgcn_exp2f(x)
#endif
#endif
#ifndef EXP2F
#define EXP2F(x) exp2f(x)
#endif

#define MFMA16(a, b, c) __builtin_amdgcn_mfma_f32_16x16x32_f16((a), (b), (c), 0, 0, 0)

// ---------------------------------------------------------------------------
// Kernel 1: MFMA-GEMM prep (exact R9 version — best measured ~18 µs).
// out[px][o] = sum_c x[c][px] * wall[o][c]; o: 0-7 theta (log2e-scaled),
// 8-15 phi, 16-47 g. Block = 4 waves = 64-px tile; grid = N*64 = 1024.
// ---------------------------------------------------------------------------
__global__ __launch_bounds__(256, 6) void prep_kernel(
    const float* __restrict__ x,        // [N, 64, 4096]
    const float* __restrict__ w_theta,  // [8, 64]
    const float* __restrict__ w_phi,    // [8, 64]
    const float* __restrict__ w_g,      // [32, 64]
    _Float16* __restrict__ theta_out,   // [N, 4096, 8]  (pre-scaled by log2e)
    _Float16* __restrict__ phi_out,     // [N, 1024, 8]
    _Float16* __restrict__ gT_out)      // [N, 32, 1024]
{
    __shared__ __align__(16) float smem[64 * 68];   // 17.4 KB
    float* xs   = smem;        // [64 ch][68] f32 (px stride 68)
    float* pool = smem;        // [64 px][49] f32 (aliases xs after barrier)

    const int n    = blockIdx.x >> 6;
    const int rem  = blockIdx.x & 63;
    const int rg   = rem >> 1;          // row-pair 0..31 (rows 2rg, 2rg+1)
    const int half = rem & 1;           // column half (32 cols)
    const int tid  = threadIdx.x;
    const int w    = tid >> 6;          // wave = M-tile 0..3
    const int lane = tid & 63;
    const int m16  = lane & 15;
    const int quad = lane >> 4;

    // ---- B-frags from weights: B[k = kc*32 + quad*8 + j][o = t*16 + m16]
    h8 bf[3][2];
#pragma unroll
    for (int t = 0; t < 3; ++t) {
        const float* row;
        float scale = 1.0f;
        if (t == 0) {
            if (m16 < 8) { row = w_theta + m16 * 64; scale = 1.44269504f; }
            else         { row = w_phi + (m16 - 8) * 64; }
        } else if (t == 1) {
            row = w_g + m16 * 64;
        } else {
            row = w_g + (16 + m16) * 64;
        }
#pragma unroll
        for (int kc = 0; kc < 2; ++kc) {
            const float* p = row + kc * 32 + quad * 8;
            float4 a = *(const float4*)p;
            float4 b = *(const float4*)(p + 4);
            bf[t][kc][0] = (_Float16)(a.x * scale);
            bf[t][kc][1] = (_Float16)(a.y * scale);
            bf[t][kc][2] = (_Float16)(a.z * scale);
            bf[t][kc][3] = (_Float16)(a.w * scale);
            bf[t][kc][4] = (_Float16)(b.x * scale);
            bf[t][kc][5] = (_Float16)(b.y * scale);
            bf[t][kc][6] = (_Float16)(b.z * scale);
            bf[t][kc][7] = (_Float16)(b.w * scale);
        }
    }

    // ---- stage x tile: 64 ch x 64 px, float4 loads -> ds_write_b128 ----
    {
        const int ch = tid >> 2;
        const int s  = tid & 3;
        const float* xc = x + (size_t)n * CCH * LL + (size_t)ch * LL;
        float4 vv[4];
#pragma unroll
        for (int i = 0; i < 4; ++i) {
            const int f    = i * 4 + s;
            const int row  = f >> 3;
            const int colg = f & 7;
            const int l    = (rg * 2 + row) * 64 + half * 32 + colg * 4;
            vv[i] = *(const float4*)(xc + l);
        }
#pragma unroll
        for (int i = 0; i < 4; ++i) {
            const int f    = i * 4 + s;
            const int row  = f >> 3;
            const int colg = f & 7;
            *(float4*)(xs + ch * 68 + row * 32 + colg * 4) = vv[i];
        }
    }
    __syncthreads();

    // ---- A-frags: A[m = w*16 + m16][k = kc*32 + quad*8 + j] from xs ----
    h8 af[2];
#pragma unroll
    for (int kc = 0; kc < 2; ++kc) {
#pragma unroll
        for (int j = 0; j < 8; ++j) {
            float v = xs[(kc * 32 + quad * 8 + j) * 68 + w * 16 + m16];
            af[kc][j] = (_Float16)v;
        }
    }

    // ---- 6 MFMAs: 3 N-tiles x 2 K-chunks ----
    f4v cfr[3];
#pragma unroll
    for (int t = 0; t < 3; ++t) {
        f4v c = {0.f, 0.f, 0.f, 0.f};
        c = MFMA16(af[0], bf[t][0], c);
        c = MFMA16(af[1], bf[t][1], c);
        cfr[t] = c;
    }
    __syncthreads();   // all xs reads done -> pool may alias

    // ---- C -> pool[px][o]: D row = quad*4+r (px-local), col = m16
    {
#pragma unroll
        for (int t = 0; t < 3; ++t) {
#pragma unroll
            for (int r = 0; r < 4; ++r)
                pool[(w * 16 + quad * 4 + r) * 49 + t * 16 + m16] = cfr[t][r];
        }
    }
    __syncthreads();

    // ---- theta store: one thread per px, h8
    if (tid < 64) {
        const int px  = tid;
        const int row = px >> 5, col = px & 31;
        const int l   = (rg * 2 + row) * 64 + half * 32 + col;
        const float* pr = pool + px * 49;
        h8 tv;
#pragma unroll
        for (int k = 0; k < 8; ++k) tv[k] = (_Float16)pr[k];
        *(h8*)(theta_out + ((size_t)n * LL + l) * 8) = tv;
    }

    // ---- 2x2 maxpool: 16 pooled cols x 40 features
    const int d_base = rg * 32 + half * 16;
    for (int idx = tid; idx < 640; idx += 256) {
        const int f40 = idx >> 4;       // 0..7 phi, 8..39 g
        const int pc  = idx & 15;
        const int fcol = 8 + f40;
        float v = fmaxf(fmaxf(pool[(2 * pc) * 49 + fcol],      pool[(2 * pc + 1) * 49 + fcol]),
                        fmaxf(pool[(32 + 2 * pc) * 49 + fcol], pool[(33 + 2 * pc) * 49 + fcol]));
        const int d = d_base + pc;
        if (f40 < 8) phi_out[((size_t)n * DD + d) * 8 + f40] = (_Float16)v;
        else         gT_out[((size_t)n * 32 + (f40 - 8)) * DD + d] = (_Float16)v;
    }
}

// ---------------------------------------------------------------------------
// Kernel 2: attn, R14. Verified R12 math (MFMA QK^T, K=8 padded to 32,
// permuted gT k<->d map so S^T lands directly in the PV A-frag).
// Resource analysis of the two failures:
//   R12: live set ~80 regs, launch_bounds(256,8) = 64-reg cap  -> spill.
//   R13: 128-reg cap, but +64-reg gT prefetch = live ~150      -> spill.
// R14 = 128-reg cap AND the small live set: launch_bounds(256,4), gT
// b-frags loaded per-chunk inside a FULLY unrolled loop (compiler hoists
// next-chunk loads into the current chunk's MFMA+exp window using the
// free headroom), wof loaded post-loop, ssum split 2-way.
// ---------------------------------------------------------------------------
__global__ __launch_bounds__(256, 4) void attn_kernel(
    const float*    __restrict__ x,       // [N, 64, 4096]
    const _Float16* __restrict__ theta,   // [N, 4096, 8]
    const _Float16* __restrict__ phi,     // [N, 1024, 8]
    const _Float16* __restrict__ gT,      // [N, 32, 1024]
    const float*    __restrict__ w_o,     // [64, 32]
    const float*    __restrict__ gamma_p, // scalar
    float*          __restrict__ out)     // [N, 64, 4096]
{
    // phi_s: [1024][8] f16 = 16384 B (unpadded).
    // red [4][32][37] f32 = 18944 B aliases phi_s; ssum at +18944 (512 B);
    // out_s [32][68] f32 = 8704 B aliases red after the combine barrier.
    __shared__ __align__(16) char smem[18944 + 512];
    _Float16* phi_s  = (_Float16*)smem;
    float*    red    = (float*)smem;                // [4][32][37]
    float*    out_s  = (float*)smem;                // [32][68]
    float*    ssum_s = (float*)(smem + 18944);      // [4][32]

    const int n    = blockIdx.x >> 7;
    const int lblk = blockIdx.x & 127;
    const int tid  = threadIdx.x;
    const int h    = tid >> 6;            // D-quarter 0..3 (one per wave)
    const int lane = tid & 63;
    const int m16  = lane & 15;
    const int quad = lane >> 4;
    const int l0   = lblk * 32;           // block query base (32 q)

    const _Float16* gT_n = gT + (size_t)n * 32 * DD;

    // ---- stage full phi[n] into LDS, plain layout [d][8]
    {
        const float4* ps = (const float4*)(phi + (size_t)n * DD * 8);
        float4* pd = (float4*)phi_s;
#pragma unroll
        for (int i = 0; i < 4; ++i) {
            const int d = tid + 256 * i;
            pd[d] = ps[d];
        }
    }

    // theta rows for this block's two 16-q M-tiles -> S^T B-frags
    // B[k=quad*8+j][n=q=m16] = theta[q][k]; real k<8 -> quad 0 only
    const h8 zero8 = {};
    h8 bq0 = zero8, bq1 = zero8;
    if (quad == 0) {
        bq0 = *(const h8*)(theta + ((size_t)n * LL + l0 + m16) * 8);
        bq1 = *(const h8*)(theta + ((size_t)n * LL + l0 + 16 + m16) * 8);
    }

    __syncthreads();   // phi_s ready

    f4v c00 = {0.f, 0.f, 0.f, 0.f}, c01 = c00, c10 = c00, c11 = c00;
    float ssum0a = 0.f, ssum0b = 0.f, ssum1a = 0.f, ssum1b = 0.f;

    // per-lane bases
    const _Float16* gq0 = gT_n + (size_t)m16 * DD + h * 256;        // ch-tile 0
    const _Float16* gq1 = gT_n + (size_t)(16 + m16) * DD + h * 256; // ch-tile 1
    const _Float16* ph_base = phi_s + (size_t)(h * 256 + m16) * 8;  // quad0 rows

#pragma unroll
    for (int c = 0; c < 8; ++c) {
        const int d0 = c * 32;

        // gT B-frags with the permuted k<->d map (2 x b64 per ch-tile);
        // loaded per-chunk -- full unroll lets the compiler hoist these
        // into the previous chunk's compute window.
        h4 b0lo = *(const h4*)(gq0 + d0 + quad * 4);
        h4 b0hi = *(const h4*)(gq0 + d0 + 16 + quad * 4);
        h4 b1lo = *(const h4*)(gq1 + d0 + quad * 4);
        h4 b1hi = *(const h4*)(gq1 + d0 + 16 + quad * 4);
        h8 b0 = __builtin_shufflevector(b0lo, b0hi, 0, 1, 2, 3, 4, 5, 6, 7);
        h8 b1 = __builtin_shufflevector(b1lo, b1hi, 0, 1, 2, 3, 4, 5, 6, 7);

        // phi A-frags for d-tiles: A[m=d_local=m16][k=quad*8+j];
        // real k<8 -> only quad 0 loads, others stay zero.
        h8 ap0 = zero8, ap1 = zero8;
        if (quad == 0) {
            ap0 = *(const h8*)(ph_base + d0 * 8);
            ap1 = *(const h8*)(ph_base + (d0 + 16) * 8);
        }

        const f4v z4 = {0.f, 0.f, 0.f, 0.f};

        // ---- all 4 S-MFMAs back-to-back (pipeline the matrix unit)
        f4v s00 = MFMA16(ap0, bq0, z4);   // d-tile0 x q-tile0
        f4v s10 = MFMA16(ap1, bq0, z4);   // d-tile1 x q-tile0
        f4v s01 = MFMA16(ap0, bq1, z4);   // d-tile0 x q-tile1
        f4v s11 = MFMA16(ap1, bq1, z4);   // d-tile1 x q-tile1

        // ---- exp -> PV A-frags (theta pre-scaled by log2e)
        h8 a0, a1;
#pragma unroll
        for (int r = 0; r < 4; ++r) {
            float e0 = EXP2F(s00[r]); ssum0a += e0; a0[r]     = (_Float16)e0;
            float f0 = EXP2F(s10[r]); ssum0b += f0; a0[4 + r] = (_Float16)f0;
            float e1 = EXP2F(s01[r]); ssum1a += e1; a1[r]     = (_Float16)e1;
            float f1 = EXP2F(s11[r]); ssum1b += f1; a1[4 + r] = (_Float16)f1;
        }

        // ---- PV accumulate
        c00 = MFMA16(a0, b0, c00);
        c01 = MFMA16(a0, b1, c01);
        c10 = MFMA16(a1, b0, c10);
        c11 = MFMA16(a1, b1, c11);
    }

    float ssum0 = ssum0a + ssum0b;
    float ssum1 = ssum1a + ssum1b;

    // quarter-D softmax denominators (quads hold disjoint d)
    ssum0 += __shfl_xor(ssum0, 16); ssum0 += __shfl_xor(ssum0, 32);
    ssum1 += __shfl_xor(ssum1, 16); ssum1 += __shfl_xor(ssum1, 32);
    if (quad == 0) {
        ssum_s[h * 32 + m16]      = ssum0;   // beyond phi_s use: safe now
        ssum_s[h * 32 + 16 + m16] = ssum1;
    }
    __syncthreads();   // ALL waves done reading phi_s -> red may alias it

    // write partial C (C layout: row q = quad*4+r, col ch = m16) into red
    {
        float* rg = red + (size_t)h * 32 * 37;
#pragma unroll
        for (int r = 0; r < 4; ++r) {
            const int rr = quad * 4 + r;
            rg[rr * 37 + m16]             = c00[r];
            rg[rr * 37 + 16 + m16]        = c01[r];
            rg[(16 + rr) * 37 + m16]      = c10[r];
            rg[(16 + rr) * 37 + 16 + m16] = c11[r];
        }
    }
    __syncthreads();

    // w_o B-frags for this wave's och-pair: och = m16 + 16*(vp*2+i)
    // (loaded post-loop to keep the hot-loop register window small)
    const int vp = h >> 1;
    h8 wof[2];
#pragma unroll
    for (int i = 0; i < 2; ++i) {
        const float* wr = w_o + (size_t)(m16 + 16 * (vp * 2 + i)) * 32 + quad * 8;
        float4 wa = *(const float4*)wr;
        float4 wb = *(const float4*)(wr + 4);
        wof[i][0] = (_Float16)wa.x; wof[i][1] = (_Float16)wa.y;
        wof[i][2] = (_Float16)wa.z; wof[i][3] = (_Float16)wa.w;
        wof[i][4] = (_Float16)wb.x; wof[i][5] = (_Float16)wb.y;
        wof[i][6] = (_Float16)wb.z; wof[i][7] = (_Float16)wb.w;
    }

    // combine 4 quarters + normalize + pack A-frag.
    // wave h projects M-tile t = h&1: q = t*16 + m16, k = gch = quad*8+j
    const int t = h & 1;
    h8 pa;
    {
        const int q = t * 16 + m16;
        const float* rq = red + q * 37 + quad * 8;
        float ss = ssum_s[q] + ssum_s[32 + q] + ssum_s[64 + q] + ssum_s[96 + q];
        float inv = 1.0f / ss;
#pragma unroll
        for (int j = 0; j < 8; ++j) {
            float sv = rq[j] + rq[32 * 37 + j] + rq[64 * 37 + j] + rq[96 * 37 + j];
            pa[j] = (_Float16)(sv * inv);
        }
    }
    __syncthreads();   // everyone done reading red -> safe to alias out_s

    // projection: D[row = local q = quad*4+r][col = och], q = t*16 + quad*4+r
    const f4v zero = {0.f, 0.f, 0.f, 0.f};
#pragma unroll
    for (int i = 0; i < 2; ++i) {
        f4v pv = MFMA16(pa, wof[i], zero);
        const int och = m16 + 16 * (vp * 2 + i);
        float* od = out_s + (size_t)(t * 16 + quad * 4) * 68 + och;
#pragma unroll
        for (int r = 0; r < 4; ++r) od[r * 68] = pv[r];
    }
    __syncthreads();

    // coalesced store + residual: thread -> och = tid>>2, 8 q from (tid&3)*8
    const float gamma = gamma_p[0];
    const int soch = tid >> 2;
    const int qoff = (tid & 3) * 8;
    const float* xrow = x   + (size_t)n * CCH * LL + (size_t)soch * LL + l0 + qoff;
    float*       orow = out + (size_t)n * CCH * LL + (size_t)soch * LL + l0 + qoff;
#pragma unroll
    for (int i = 0; i < 2; ++i) {
        float4 xv = *(const float4*)(xrow + i * 4);
        float4 ov;
        ov.x = xv.x + gamma * out_s[(qoff + i * 4)     * 68 + soch];
        ov.y = xv.y + gamma * out_s[(qoff + i * 4 + 1) * 68 + soch];
        ov.z = xv.z + gamma * out_s[(qoff + i * 4 + 2) * 68 + soch];
        ov.w = xv.w + gamma * out_s[(qoff + i * 4 + 3) * 68 + soch];
        *(float4*)(orow + i * 4) = ov;
    }
}

// ---------------------------------------------------------------------------
extern "C" void kernel_launch(void* const* d_in, const int* in_sizes, int n_in,
                              void* d_out, int out_size, void* d_ws, size_t ws_size,
                              hipStream_t stream) {
    const float* x       = (const float*)d_in[0];
    const float* w_theta = (const float*)d_in[1];
    const float* w_phi   = (const float*)d_in[2];
    const float* w_g     = (const float*)d_in[3];
    const float* w_o     = (const float*)d_in[4];
    const float* gamma   = (const float*)d_in[5];
    float* out = (float*)d_out;

    // ws layout (f16): theta 1 MB | phi 256 KB | gT 1 MB
    _Float16* theta_h = (_Float16*)d_ws;                    // N*L*8
    _Float16* phi_h   = theta_h + (size_t)NB * LL * 8;      // N*D*8
    _Float16* gT_h    = phi_h   + (size_t)NB * DD * 8;      // N*32*D

    prep_kernel<<<1024, 256, 0, stream>>>(x, w_theta, w_phi, w_g,
                                          theta_h, phi_h, gT_h);
    attn_kernel<<<2048, 256, 0, stream>>>(x, theta_h, phi_h, gT_h,
                                          w_o, gamma, out);
}

// Round 5
// 119.493 us; speedup vs baseline: 1.2192x; 1.1768x over previous
//
#include <hip/hip_runtime.h>
#include <hip/hip_bf16.h>
#include <hip/hip_fp16.h>

#define NB 16
#define CCH 64
#define LL 4096   // 64*64
#define DD 1024   // 32*32

typedef _Float16 h8 __attribute__((ext_vector_type(8)));
typedef _Float16 h4 __attribute__((ext_vector_type(4)));
typedef _Float16 h2 __attribute__((ext_vector_type(2)));
typedef float    f4v __attribute__((ext_vector_type(4)));

#if defined(__has_builtin)
#if __has_builtin(__builtin_amdgcn_exp2f)
#define EXP2F(x) __builtin_amdgcn_exp2f(x)
#endif
#endif
#ifndef EXP2F
#define EXP2F(x) exp2f(x)
#endif

#define MFMA16(a, b, c) __builtin_amdgcn_mfma_f32_16x16x32_f16((a), (b), (c), 0, 0, 0)

// ---------------------------------------------------------------------------
// Kernel 1: MFMA-GEMM prep (exact R9 version — best measured ~18 µs).
// out[px][o] = sum_c x[c][px] * wall[o][c]; o: 0-7 theta (log2e-scaled),
// 8-15 phi, 16-47 g. Block = 4 waves = 64-px tile; grid = N*64 = 1024.
// ---------------------------------------------------------------------------
__global__ __launch_bounds__(256, 6) void prep_kernel(
    const float* __restrict__ x,        // [N, 64, 4096]
    const float* __restrict__ w_theta,  // [8, 64]
    const float* __restrict__ w_phi,    // [8, 64]
    const float* __restrict__ w_g,      // [32, 64]
    _Float16* __restrict__ theta_out,   // [N, 4096, 8]  (pre-scaled by log2e)
    _Float16* __restrict__ phi_out,     // [N, 1024, 8]
    _Float16* __restrict__ gT_out)      // [N, 32, 1024]
{
    __shared__ __align__(16) float smem[64 * 68];   // 17.4 KB
    float* xs   = smem;        // [64 ch][68] f32 (px stride 68)
    float* pool = smem;        // [64 px][49] f32 (aliases xs after barrier)

    const int n    = blockIdx.x >> 6;
    const int rem  = blockIdx.x & 63;
    const int rg   = rem >> 1;          // row-pair 0..31 (rows 2rg, 2rg+1)
    const int half = rem & 1;           // column half (32 cols)
    const int tid  = threadIdx.x;
    const int w    = tid >> 6;          // wave = M-tile 0..3
    const int lane = tid & 63;
    const int m16  = lane & 15;
    const int quad = lane >> 4;

    // ---- B-frags from weights: B[k = kc*32 + quad*8 + j][o = t*16 + m16]
    h8 bf[3][2];
#pragma unroll
    for (int t = 0; t < 3; ++t) {
        const float* row;
        float scale = 1.0f;
        if (t == 0) {
            if (m16 < 8) { row = w_theta + m16 * 64; scale = 1.44269504f; }
            else         { row = w_phi + (m16 - 8) * 64; }
        } else if (t == 1) {
            row = w_g + m16 * 64;
        } else {
            row = w_g + (16 + m16) * 64;
        }
#pragma unroll
        for (int kc = 0; kc < 2; ++kc) {
            const float* p = row + kc * 32 + quad * 8;
            float4 a = *(const float4*)p;
            float4 b = *(const float4*)(p + 4);
            bf[t][kc][0] = (_Float16)(a.x * scale);
            bf[t][kc][1] = (_Float16)(a.y * scale);
            bf[t][kc][2] = (_Float16)(a.z * scale);
            bf[t][kc][3] = (_Float16)(a.w * scale);
            bf[t][kc][4] = (_Float16)(b.x * scale);
            bf[t][kc][5] = (_Float16)(b.y * scale);
            bf[t][kc][6] = (_Float16)(b.z * scale);
            bf[t][kc][7] = (_Float16)(b.w * scale);
        }
    }

    // ---- stage x tile: 64 ch x 64 px, float4 loads -> ds_write_b128 ----
    {
        const int ch = tid >> 2;
        const int s  = tid & 3;
        const float* xc = x + (size_t)n * CCH * LL + (size_t)ch * LL;
        float4 vv[4];
#pragma unroll
        for (int i = 0; i < 4; ++i) {
            const int f    = i * 4 + s;
            const int row  = f >> 3;
            const int colg = f & 7;
            const int l    = (rg * 2 + row) * 64 + half * 32 + colg * 4;
            vv[i] = *(const float4*)(xc + l);
        }
#pragma unroll
        for (int i = 0; i < 4; ++i) {
            const int f    = i * 4 + s;
            const int row  = f >> 3;
            const int colg = f & 7;
            *(float4*)(xs + ch * 68 + row * 32 + colg * 4) = vv[i];
        }
    }
    __syncthreads();

    // ---- A-frags: A[m = w*16 + m16][k = kc*32 + quad*8 + j] from xs ----
    h8 af[2];
#pragma unroll
    for (int kc = 0; kc < 2; ++kc) {
#pragma unroll
        for (int j = 0; j < 8; ++j) {
            float v = xs[(kc * 32 + quad * 8 + j) * 68 + w * 16 + m16];
            af[kc][j] = (_Float16)v;
        }
    }

    // ---- 6 MFMAs: 3 N-tiles x 2 K-chunks ----
    f4v cfr[3];
#pragma unroll
    for (int t = 0; t < 3; ++t) {
        f4v c = {0.f, 0.f, 0.f, 0.f};
        c = MFMA16(af[0], bf[t][0], c);
        c = MFMA16(af[1], bf[t][1], c);
        cfr[t] = c;
    }
    __syncthreads();   // all xs reads done -> pool may alias

    // ---- C -> pool[px][o]: D row = quad*4+r (px-local), col = m16
    {
#pragma unroll
        for (int t = 0; t < 3; ++t) {
#pragma unroll
            for (int r = 0; r < 4; ++r)
                pool[(w * 16 + quad * 4 + r) * 49 + t * 16 + m16] = cfr[t][r];
        }
    }
    __syncthreads();

    // ---- theta store: one thread per px, h8
    if (tid < 64) {
        const int px  = tid;
        const int row = px >> 5, col = px & 31;
        const int l   = (rg * 2 + row) * 64 + half * 32 + col;
        const float* pr = pool + px * 49;
        h8 tv;
#pragma unroll
        for (int k = 0; k < 8; ++k) tv[k] = (_Float16)pr[k];
        *(h8*)(theta_out + ((size_t)n * LL + l) * 8) = tv;
    }

    // ---- 2x2 maxpool: 16 pooled cols x 40 features
    const int d_base = rg * 32 + half * 16;
    for (int idx = tid; idx < 640; idx += 256) {
        const int f40 = idx >> 4;       // 0..7 phi, 8..39 g
        const int pc  = idx & 15;
        const int fcol = 8 + f40;
        float v = fmaxf(fmaxf(pool[(2 * pc) * 49 + fcol],      pool[(2 * pc + 1) * 49 + fcol]),
                        fmaxf(pool[(32 + 2 * pc) * 49 + fcol], pool[(33 + 2 * pc) * 49 + fcol]));
        const int d = d_base + pc;
        if (f40 < 8) phi_out[((size_t)n * DD + d) * 8 + f40] = (_Float16)v;
        else         gT_out[((size_t)n * 32 + (f40 - 8)) * DD + d] = (_Float16)v;
    }
}

// ---------------------------------------------------------------------------
// Kernel 2: attn, R15. Verified R12 math (MFMA QK^T, K=8 padded to 32,
// permuted gT k<->d map so S^T lands directly in the PV A-frag).
// Spill matrix from R12-R14 counters:
//   R12: live ~80, cap 64 (256,8)            -> spill (WRITE 61 MB)
//   R13: cap 128, explicit prefetch live~150 -> spill (WRITE 96 MB)
//   R14: cap 128, FULL unroll -> compiler hoisted all gT loads = R13
//        (counters identical: WRITE 94 MB)   -> spill
// R15 = cap 128 (launch_bounds(256,4)) + "#pragma unroll 2": load hoisting
// bounded to 2 iterations (+16 regs), live ~100 < 128 -> no spill, 2
// independent chains of ILP + 16 waves/CU TLP hide gT L2 latency.
// Also: phi A-frag LDS reads made unconditional (quads 1-3 multiply B=0,
// only ONE operand of the padded K-region needs zeros; bq is zeroed).
// Falsifiable: WRITE_SIZE must drop 94 -> ~16.5 MB, else revert to R9 attn.
// ---------------------------------------------------------------------------
__global__ __launch_bounds__(256, 4) void attn_kernel(
    const float*    __restrict__ x,       // [N, 64, 4096]
    const _Float16* __restrict__ theta,   // [N, 4096, 8]
    const _Float16* __restrict__ phi,     // [N, 1024, 8]
    const _Float16* __restrict__ gT,      // [N, 32, 1024]
    const float*    __restrict__ w_o,     // [64, 32]
    const float*    __restrict__ gamma_p, // scalar
    float*          __restrict__ out)     // [N, 64, 4096]
{
    // phi_s: [1024][8] f16 = 16384 B (unpadded).
    // red [4][32][37] f32 = 18944 B aliases phi_s; ssum at +18944 (512 B);
    // out_s [32][68] f32 = 8704 B aliases red after the combine barrier.
    __shared__ __align__(16) char smem[18944 + 512];
    _Float16* phi_s  = (_Float16*)smem;
    float*    red    = (float*)smem;                // [4][32][37]
    float*    out_s  = (float*)smem;                // [32][68]
    float*    ssum_s = (float*)(smem + 18944);      // [4][32]

    const int n    = blockIdx.x >> 7;
    const int lblk = blockIdx.x & 127;
    const int tid  = threadIdx.x;
    const int h    = tid >> 6;            // D-quarter 0..3 (one per wave)
    const int lane = tid & 63;
    const int m16  = lane & 15;
    const int quad = lane >> 4;
    const int l0   = lblk * 32;           // block query base (32 q)

    const _Float16* gT_n = gT + (size_t)n * 32 * DD;

    // ---- stage full phi[n] into LDS, plain layout [d][8]
    {
        const float4* ps = (const float4*)(phi + (size_t)n * DD * 8);
        float4* pd = (float4*)phi_s;
#pragma unroll
        for (int i = 0; i < 4; ++i) {
            const int d = tid + 256 * i;
            pd[d] = ps[d];
        }
    }

    // theta rows for this block's two 16-q M-tiles -> S^T B-frags
    // B[k=quad*8+j][n=q=m16] = theta[q][k]; real k<8 -> quad 0 only
    const h8 zero8 = {};
    h8 bq0 = zero8, bq1 = zero8;
    if (quad == 0) {
        bq0 = *(const h8*)(theta + ((size_t)n * LL + l0 + m16) * 8);
        bq1 = *(const h8*)(theta + ((size_t)n * LL + l0 + 16 + m16) * 8);
    }

    __syncthreads();   // phi_s ready

    f4v c00 = {0.f, 0.f, 0.f, 0.f}, c01 = c00, c10 = c00, c11 = c00;
    float ssum0a = 0.f, ssum0b = 0.f, ssum1a = 0.f, ssum1b = 0.f;

    // per-lane bases
    const _Float16* gq0 = gT_n + (size_t)m16 * DD + h * 256;        // ch-tile 0
    const _Float16* gq1 = gT_n + (size_t)(16 + m16) * DD + h * 256; // ch-tile 1
    const _Float16* ph_base = phi_s + (size_t)(h * 256 + m16) * 8;  // quad0 rows

#pragma unroll 2
    for (int c = 0; c < 8; ++c) {
        const int d0 = c * 32;

        // gT B-frags with the permuted k<->d map (2 x b64 per ch-tile)
        h4 b0lo = *(const h4*)(gq0 + d0 + quad * 4);
        h4 b0hi = *(const h4*)(gq0 + d0 + 16 + quad * 4);
        h4 b1lo = *(const h4*)(gq1 + d0 + quad * 4);
        h4 b1hi = *(const h4*)(gq1 + d0 + 16 + quad * 4);
        h8 b0 = __builtin_shufflevector(b0lo, b0hi, 0, 1, 2, 3, 4, 5, 6, 7);
        h8 b1 = __builtin_shufflevector(b1lo, b1hi, 0, 1, 2, 3, 4, 5, 6, 7);

        // phi A-frags, UNCONDITIONAL (LDS broadcast): quads 1-3 supply the
        // k>=8 rows of A, which multiply bq's zeros -> contribute nothing.
        h8 ap0 = *(const h8*)(ph_base + d0 * 8);
        h8 ap1 = *(const h8*)(ph_base + (d0 + 16) * 8);

        const f4v z4 = {0.f, 0.f, 0.f, 0.f};

        // ---- all 4 S-MFMAs back-to-back (pipeline the matrix unit)
        f4v s00 = MFMA16(ap0, bq0, z4);   // d-tile0 x q-tile0
        f4v s10 = MFMA16(ap1, bq0, z4);   // d-tile1 x q-tile0
        f4v s01 = MFMA16(ap0, bq1, z4);   // d-tile0 x q-tile1
        f4v s11 = MFMA16(ap1, bq1, z4);   // d-tile1 x q-tile1

        // ---- exp -> PV A-frags (theta pre-scaled by log2e)
        h8 a0, a1;
#pragma unroll
        for (int r = 0; r < 4; ++r) {
            float e0 = EXP2F(s00[r]); ssum0a += e0; a0[r]     = (_Float16)e0;
            float f0 = EXP2F(s10[r]); ssum0b += f0; a0[4 + r] = (_Float16)f0;
            float e1 = EXP2F(s01[r]); ssum1a += e1; a1[r]     = (_Float16)e1;
            float f1 = EXP2F(s11[r]); ssum1b += f1; a1[4 + r] = (_Float16)f1;
        }

        // ---- PV accumulate
        c00 = MFMA16(a0, b0, c00);
        c01 = MFMA16(a0, b1, c01);
        c10 = MFMA16(a1, b0, c10);
        c11 = MFMA16(a1, b1, c11);
    }

    float ssum0 = ssum0a + ssum0b;
    float ssum1 = ssum1a + ssum1b;

    // quarter-D softmax denominators (quads hold disjoint d)
    ssum0 += __shfl_xor(ssum0, 16); ssum0 += __shfl_xor(ssum0, 32);
    ssum1 += __shfl_xor(ssum1, 16); ssum1 += __shfl_xor(ssum1, 32);
    if (quad == 0) {
        ssum_s[h * 32 + m16]      = ssum0;   // beyond phi_s use: safe now
        ssum_s[h * 32 + 16 + m16] = ssum1;
    }
    __syncthreads();   // ALL waves done reading phi_s -> red may alias it

    // write partial C (C layout: row q = quad*4+r, col ch = m16) into red
    {
        float* rg = red + (size_t)h * 32 * 37;
#pragma unroll
        for (int r = 0; r < 4; ++r) {
            const int rr = quad * 4 + r;
            rg[rr * 37 + m16]             = c00[r];
            rg[rr * 37 + 16 + m16]        = c01[r];
            rg[(16 + rr) * 37 + m16]      = c10[r];
            rg[(16 + rr) * 37 + 16 + m16] = c11[r];
        }
    }
    __syncthreads();

    // w_o B-frags for this wave's och-pair: och = m16 + 16*(vp*2+i)
    // (loaded post-loop to keep the hot-loop register window small)
    const int vp = h >> 1;
    h8 wof[2];
#pragma unroll
    for (int i = 0; i < 2; ++i) {
        const float* wr = w_o + (size_t)(m16 + 16 * (vp * 2 + i)) * 32 + quad * 8;
        float4 wa = *(const float4*)wr;
        float4 wb = *(const float4*)(wr + 4);
        wof[i][0] = (_Float16)wa.x; wof[i][1] = (_Float16)wa.y;
        wof[i][2] = (_Float16)wa.z; wof[i][3] = (_Float16)wa.w;
        wof[i][4] = (_Float16)wb.x; wof[i][5] = (_Float16)wb.y;
        wof[i][6] = (_Float16)wb.z; wof[i][7] = (_Float16)wb.w;
    }

    // combine 4 quarters + normalize + pack A-frag.
    // wave h projects M-tile t = h&1: q = t*16 + m16, k = gch = quad*8+j
    const int t = h & 1;
    h8 pa;
    {
        const int q = t * 16 + m16;
        const float* rq = red + q * 37 + quad * 8;
        float ss = ssum_s[q] + ssum_s[32 + q] + ssum_s[64 + q] + ssum_s[96 + q];
        float inv = 1.0f / ss;
#pragma unroll
        for (int j = 0; j < 8; ++j) {
            float sv = rq[j] + rq[32 * 37 + j] + rq[64 * 37 + j] + rq[96 * 37 + j];
            pa[j] = (_Float16)(sv * inv);
        }
    }
    __syncthreads();   // everyone done reading red -> safe to alias out_s

    // projection: D[row = local q = quad*4+r][col = och], q = t*16 + quad*4+r
    const f4v zero = {0.f, 0.f, 0.f, 0.f};
#pragma unroll
    for (int i = 0; i < 2; ++i) {
        f4v pv = MFMA16(pa, wof[i], zero);
        const int och = m16 + 16 * (vp * 2 + i);
        float* od = out_s + (size_t)(t * 16 + quad * 4) * 68 + och;
#pragma unroll
        for (int r = 0; r < 4; ++r) od[r * 68] = pv[r];
    }
    __syncthreads();

    // coalesced store + residual: thread -> och = tid>>2, 8 q from (tid&3)*8
    const float gamma = gamma_p[0];
    const int soch = tid >> 2;
    const int qoff = (tid & 3) * 8;
    const float* xrow = x   + (size_t)n * CCH * LL + (size_t)soch * LL + l0 + qoff;
    float*       orow = out + (size_t)n * CCH * LL + (size_t)soch * LL + l0 + qoff;
#pragma unroll
    for (int i = 0; i < 2; ++i) {
        float4 xv = *(const float4*)(xrow + i * 4);
        float4 ov;
        ov.x = xv.x + gamma * out_s[(qoff + i * 4)     * 68 + soch];
        ov.y = xv.y + gamma * out_s[(qoff + i * 4 + 1) * 68 + soch];
        ov.z = xv.z + gamma * out_s[(qoff + i * 4 + 2) * 68 + soch];
        ov.w = xv.w + gamma * out_s[(qoff + i * 4 + 3) * 68 + soch];
        *(float4*)(orow + i * 4) = ov;
    }
}

// ---------------------------------------------------------------------------
extern "C" void kernel_launch(void* const* d_in, const int* in_sizes, int n_in,
                              void* d_out, int out_size, void* d_ws, size_t ws_size,
                              hipStream_t stream) {
    const float* x       = (const float*)d_in[0];
    const float* w_theta = (const float*)d_in[1];
    const float* w_phi   = (const float*)d_in[2];
    const float* w_g     = (const float*)d_in[3];
    const float* w_o     = (const float*)d_in[4];
    const float* gamma   = (const float*)d_in[5];
    float* out = (float*)d_out;

    // ws layout (f16): theta 1 MB | phi 256 KB | gT 1 MB
    _Float16* theta_h = (_Float16*)d_ws;                    // N*L*8
    _Float16* phi_h   = theta_h + (size_t)NB * LL * 8;      // N*D*8
    _Float16* gT_h    = phi_h   + (size_t)NB * DD * 8;      // N*32*D

    prep_kernel<<<1024, 256, 0, stream>>>(x, w_theta, w_phi, w_g,
                                          theta_h, phi_h, gT_h);
    attn_kernel<<<2048, 256, 0, stream>>>(x, theta_h, phi_h, gT_h,
                                          w_o, gamma, out);
}

// Round 6
// 112.000 us; speedup vs baseline: 1.3008x; 1.0669x over previous
//
#include <hip/hip_runtime.h>
#include <hip/hip_bf16.h>
#include <hip/hip_fp16.h>

#define NB 16
#define CCH 64
#define LL 4096   // 64*64
#define DD 1024   // 32*32

typedef _Float16 h8 __attribute__((ext_vector_type(8)));
typedef _Float16 h2 __attribute__((ext_vector_type(2)));
typedef float    f4v __attribute__((ext_vector_type(4)));

#if defined(__has_builtin)
#if __has_builtin(__builtin_amdgcn_fdot2)
#define HAVE_FDOT2 1
#endif
#if __has_builtin(__builtin_amdgcn_exp2f)
#define EXP2F(x) __builtin_amdgcn_exp2f(x)
#endif
#endif
#ifndef EXP2F
#define EXP2F(x) exp2f(x)
#endif

static __device__ __forceinline__ float fdot2f(h2 a, h2 b, float c) {
#ifdef HAVE_FDOT2
    return __builtin_amdgcn_fdot2(a, b, c, false);
#else
    return c + (float)a[0] * (float)b[0] + (float)a[1] * (float)b[1];
#endif
}

#define MFMA16(a, b, c) __builtin_amdgcn_mfma_f32_16x16x32_f16((a), (b), (c), 0, 0, 0)

// ---------------------------------------------------------------------------
// Kernel 1: MFMA-GEMM prep (exact R9 version — best measured ~18 µs).
// out[px][o] = sum_c x[c][px] * wall[o][c]; o: 0-7 theta (log2e-scaled),
// 8-15 phi, 16-47 g. Block = 4 waves = 64-px tile; grid = N*64 = 1024.
// ---------------------------------------------------------------------------
__global__ __launch_bounds__(256, 6) void prep_kernel(
    const float* __restrict__ x,        // [N, 64, 4096]
    const float* __restrict__ w_theta,  // [8, 64]
    const float* __restrict__ w_phi,    // [8, 64]
    const float* __restrict__ w_g,      // [32, 64]
    _Float16* __restrict__ theta_out,   // [N, 4096, 8]  (pre-scaled by log2e)
    _Float16* __restrict__ phi_out,     // [N, 1024, 8]
    _Float16* __restrict__ gT_out)      // [N, 32, 1024]
{
    __shared__ __align__(16) float smem[64 * 68];   // 17.4 KB
    float* xs   = smem;        // [64 ch][68] f32 (px stride 68)
    float* pool = smem;        // [64 px][49] f32 (aliases xs after barrier)

    const int n    = blockIdx.x >> 6;
    const int rem  = blockIdx.x & 63;
    const int rg   = rem >> 1;          // row-pair 0..31 (rows 2rg, 2rg+1)
    const int half = rem & 1;           // column half (32 cols)
    const int tid  = threadIdx.x;
    const int w    = tid >> 6;          // wave = M-tile 0..3
    const int lane = tid & 63;
    const int m16  = lane & 15;
    const int quad = lane >> 4;

    // ---- B-frags from weights: B[k = kc*32 + quad*8 + j][o = t*16 + m16]
    h8 bf[3][2];
#pragma unroll
    for (int t = 0; t < 3; ++t) {
        const float* row;
        float scale = 1.0f;
        if (t == 0) {
            if (m16 < 8) { row = w_theta + m16 * 64; scale = 1.44269504f; }
            else         { row = w_phi + (m16 - 8) * 64; }
        } else if (t == 1) {
            row = w_g + m16 * 64;
        } else {
            row = w_g + (16 + m16) * 64;
        }
#pragma unroll
        for (int kc = 0; kc < 2; ++kc) {
            const float* p = row + kc * 32 + quad * 8;
            float4 a = *(const float4*)p;
            float4 b = *(const float4*)(p + 4);
            bf[t][kc][0] = (_Float16)(a.x * scale);
            bf[t][kc][1] = (_Float16)(a.y * scale);
            bf[t][kc][2] = (_Float16)(a.z * scale);
            bf[t][kc][3] = (_Float16)(a.w * scale);
            bf[t][kc][4] = (_Float16)(b.x * scale);
            bf[t][kc][5] = (_Float16)(b.y * scale);
            bf[t][kc][6] = (_Float16)(b.z * scale);
            bf[t][kc][7] = (_Float16)(b.w * scale);
        }
    }

    // ---- stage x tile: 64 ch x 64 px, float4 loads -> ds_write_b128 ----
    {
        const int ch = tid >> 2;
        const int s  = tid & 3;
        const float* xc = x + (size_t)n * CCH * LL + (size_t)ch * LL;
        float4 vv[4];
#pragma unroll
        for (int i = 0; i < 4; ++i) {
            const int f    = i * 4 + s;
            const int row  = f >> 3;
            const int colg = f & 7;
            const int l    = (rg * 2 + row) * 64 + half * 32 + colg * 4;
            vv[i] = *(const float4*)(xc + l);
        }
#pragma unroll
        for (int i = 0; i < 4; ++i) {
            const int f    = i * 4 + s;
            const int row  = f >> 3;
            const int colg = f & 7;
            *(float4*)(xs + ch * 68 + row * 32 + colg * 4) = vv[i];
        }
    }
    __syncthreads();

    // ---- A-frags: A[m = w*16 + m16][k = kc*32 + quad*8 + j] from xs ----
    h8 af[2];
#pragma unroll
    for (int kc = 0; kc < 2; ++kc) {
#pragma unroll
        for (int j = 0; j < 8; ++j) {
            float v = xs[(kc * 32 + quad * 8 + j) * 68 + w * 16 + m16];
            af[kc][j] = (_Float16)v;
        }
    }

    // ---- 6 MFMAs: 3 N-tiles x 2 K-chunks ----
    f4v cfr[3];
#pragma unroll
    for (int t = 0; t < 3; ++t) {
        f4v c = {0.f, 0.f, 0.f, 0.f};
        c = MFMA16(af[0], bf[t][0], c);
        c = MFMA16(af[1], bf[t][1], c);
        cfr[t] = c;
    }
    __syncthreads();   // all xs reads done -> pool may alias

    // ---- C -> pool[px][o]: D row = quad*4+r (px-local), col = m16
    {
#pragma unroll
        for (int t = 0; t < 3; ++t) {
#pragma unroll
            for (int r = 0; r < 4; ++r)
                pool[(w * 16 + quad * 4 + r) * 49 + t * 16 + m16] = cfr[t][r];
        }
    }
    __syncthreads();

    // ---- theta store: one thread per px, h8
    if (tid < 64) {
        const int px  = tid;
        const int row = px >> 5, col = px & 31;
        const int l   = (rg * 2 + row) * 64 + half * 32 + col;
        const float* pr = pool + px * 49;
        h8 tv;
#pragma unroll
        for (int k = 0; k < 8; ++k) tv[k] = (_Float16)pr[k];
        *(h8*)(theta_out + ((size_t)n * LL + l) * 8) = tv;
    }

    // ---- 2x2 maxpool: 16 pooled cols x 40 features
    const int d_base = rg * 32 + half * 16;
    for (int idx = tid; idx < 640; idx += 256) {
        const int f40 = idx >> 4;       // 0..7 phi, 8..39 g
        const int pc  = idx & 15;
        const int fcol = 8 + f40;
        float v = fmaxf(fmaxf(pool[(2 * pc) * 49 + fcol],      pool[(2 * pc + 1) * 49 + fcol]),
                        fmaxf(pool[(32 + 2 * pc) * 49 + fcol], pool[(33 + 2 * pc) * 49 + fcol]));
        const int d = d_base + pc;
        if (f40 < 8) phi_out[((size_t)n * DD + d) * 8 + f40] = (_Float16)v;
        else         gT_out[((size_t)n * 32 + (f40 - 8)) * DD + d] = (_Float16)v;
    }
}

// ---------------------------------------------------------------------------
// Kernel 2: exact R9 attn (the verified-best config; total was 114.1 µs).
// Reverted from the MFMA-QK^T line (R12-R15): R15 fixed the spill
// (WRITE 16.4 MB) but still measured 45 µs at 0.69 TB/s with all pipes
// idle — consistent with co-running against the harness's 268-MB poison
// fill and being starved to leftover HBM BW. This revert is the decisive
// A/B: if this kernel also measures ~40-45 µs (not its remembered ~26),
// the duration is a harness-BW floor and we are at the roofline.
// 4-way D-split, phi in padded LDS (conflict-free quad broadcast),
// 8 blocks/CU, grid = N*128 = 2048. NO prefetch (64-VGPR cap).
// ---------------------------------------------------------------------------
__global__ __launch_bounds__(256, 8) void attn_kernel(
    const float*    __restrict__ x,       // [N, 64, 4096]
    const _Float16* __restrict__ theta,   // [N, 4096, 8]
    const _Float16* __restrict__ phi,     // [N, 1024, 8]
    const _Float16* __restrict__ gT,      // [N, 32, 1024]
    const float*    __restrict__ w_o,     // [64, 32]
    const float*    __restrict__ gamma_p, // scalar
    float*          __restrict__ out)     // [N, 64, 4096]
{
    // phi_s padded: row d at float4 index d + (d>>3) -> 1152 float4 = 18432 B
    // red [4][32][37] f32 = 18944 B aliases phi_s; ssum at +18944 (512 B);
    // out_s [32][68] f32 = 8704 B aliases red after the combine barrier.
    __shared__ __align__(16) char smem[18944 + 512];
    _Float16* phi_s  = (_Float16*)smem;
    float*    red    = (float*)smem;                // [4][32][37]
    float*    out_s  = (float*)smem;                // [32][68]
    float*    ssum_s = (float*)(smem + 18944);      // [4][32]

    const int n    = blockIdx.x >> 7;
    const int lblk = blockIdx.x & 127;
    const int tid  = threadIdx.x;
    const int h    = tid >> 6;            // D-quarter 0..3 (one per wave)
    const int lane = tid & 63;
    const int m16  = lane & 15;
    const int quad = lane >> 4;
    const int l0   = lblk * 32;           // block query base (32 q)

    const _Float16* gT_n = gT + (size_t)n * 32 * DD;

    // stage full phi[n] into padded LDS: row d -> float4 slot d + (d>>3)
    {
        const float4* ps = (const float4*)(phi + (size_t)n * DD * 8);
        float4* pd = (float4*)phi_s;
#pragma unroll
        for (int i = 0; i < 4; ++i) {
            const int d = tid + 256 * i;
            pd[d + (d >> 3)] = ps[d];
        }
    }

    // theta rows, two 16-q M-tiles: A[m=lane&15][k=quad*8+j]
    h8 th0 = *(const h8*)(theta + ((size_t)n * LL + l0 + m16) * 8);
    h8 th1 = *(const h8*)(theta + ((size_t)n * LL + l0 + 16 + m16) * 8);
    const h2* t0p = (const h2*)&th0;
    const h2* t1p = (const h2*)&th1;

    // w_o B-frags for this wave's och-pair: och = m16 + 16*(vp*2+i)
    const int vp = h >> 1;
    h8 wof[2];
#pragma unroll
    for (int i = 0; i < 2; ++i) {
        const float* wr = w_o + (size_t)(m16 + 16 * (vp * 2 + i)) * 32 + quad * 8;
        float4 wa = *(const float4*)wr;
        float4 wb = *(const float4*)(wr + 4);
        wof[i][0] = (_Float16)wa.x; wof[i][1] = (_Float16)wa.y;
        wof[i][2] = (_Float16)wa.z; wof[i][3] = (_Float16)wa.w;
        wof[i][4] = (_Float16)wb.x; wof[i][5] = (_Float16)wb.y;
        wof[i][6] = (_Float16)wb.z; wof[i][7] = (_Float16)wb.w;
    }

    __syncthreads();   // phi_s ready

    f4v c00 = {0.f, 0.f, 0.f, 0.f}, c01 = c00, c10 = c00, c11 = c00;
    float ssum0 = 0.f, ssum1 = 0.f;

    const _Float16* gr0 = gT_n + (size_t)m16 * DD + h * 256 + quad * 8;
    const _Float16* gr1 = gT_n + (size_t)(16 + m16) * DD + h * 256 + quad * 8;
    const int pb = h * 256 + quad * 8;    // this wave-quad's phi base row
    const _Float16* pr = phi_s + (size_t)(pb + (pb >> 3)) * 8;

#pragma unroll 2
    for (int c = 0; c < 8; ++c) {
        const int d0 = c * 32;
        h8 b0 = *(const h8*)(gr0 + d0);   // B[k][ch] for ch 0..15
        h8 b1 = *(const h8*)(gr1 + d0);   // ch 16..31
        const _Float16* prc = pr + c * 288;   // 32 rows + 4 pads per chunk
        h8 a0, a1;
#pragma unroll
        for (int j = 0; j < 8; ++j) {
            h8 ph = *(const h8*)(prc + j * 8);   // LDS, conflict-free broadcast
            const h2* pp = (const h2*)&ph;
            float u0 = fdot2f(t0p[0], pp[0], 0.f);
            u0 = fdot2f(t0p[1], pp[1], u0);
            float v0 = fdot2f(t0p[2], pp[2], 0.f);
            v0 = fdot2f(t0p[3], pp[3], v0);
            float u1 = fdot2f(t1p[0], pp[0], 0.f);
            u1 = fdot2f(t1p[1], pp[1], u1);
            float v1 = fdot2f(t1p[2], pp[2], 0.f);
            v1 = fdot2f(t1p[3], pp[3], v1);
            float e0 = EXP2F(u0 + v0);    // theta pre-scaled by log2e
            float e1 = EXP2F(u1 + v1);
            ssum0 += e0; ssum1 += e1;
            a0[j] = (_Float16)e0;
            a1[j] = (_Float16)e1;
        }
        c00 = MFMA16(a0, b0, c00);
        c01 = MFMA16(a0, b1, c01);
        c10 = MFMA16(a1, b0, c10);
        c11 = MFMA16(a1, b1, c11);
    }

    // quarter-D softmax denominators (quads hold disjoint d)
    ssum0 += __shfl_xor(ssum0, 16); ssum0 += __shfl_xor(ssum0, 32);
    ssum1 += __shfl_xor(ssum1, 16); ssum1 += __shfl_xor(ssum1, 32);
    if (quad == 0) {
        ssum_s[h * 32 + m16]      = ssum0;   // beyond phi_s extent: safe now
        ssum_s[h * 32 + 16 + m16] = ssum1;
    }
    __syncthreads();   // ALL waves done reading phi_s -> red may alias it

    // write partial C (C layout: row q = quad*4+r, col ch = m16) into red
    {
        float* rg = red + (size_t)h * 32 * 37;
#pragma unroll
        for (int r = 0; r < 4; ++r) {
            const int rr = quad * 4 + r;
            rg[rr * 37 + m16]             = c00[r];
            rg[rr * 37 + 16 + m16]        = c01[r];
            rg[(16 + rr) * 37 + m16]      = c10[r];
            rg[(16 + rr) * 37 + 16 + m16] = c11[r];
        }
    }
    __syncthreads();

    // combine 4 quarters + normalize + pack A-frag.
    // wave h projects M-tile t = h&1: q = t*16 + m16, k = gch = quad*8+j
    const int t = h & 1;
    h8 pa;
    {
        const int q = t * 16 + m16;
        const float* rq = red + q * 37 + quad * 8;
        float ss = ssum_s[q] + ssum_s[32 + q] + ssum_s[64 + q] + ssum_s[96 + q];
        float inv = 1.0f / ss;
#pragma unroll
        for (int j = 0; j < 8; ++j) {
            float sv = rq[j] + rq[32 * 37 + j] + rq[64 * 37 + j] + rq[96 * 37 + j];
            pa[j] = (_Float16)(sv * inv);
        }
    }
    __syncthreads();   // everyone done reading red -> safe to alias out_s

    // projection: D[row = local q = quad*4+r][col = och], q = t*16 + quad*4+r
    const f4v zero = {0.f, 0.f, 0.f, 0.f};
#pragma unroll
    for (int i = 0; i < 2; ++i) {
        f4v pv = MFMA16(pa, wof[i], zero);
        const int och = m16 + 16 * (vp * 2 + i);
        float* od = out_s + (size_t)(t * 16 + quad * 4) * 68 + och;
#pragma unroll
        for (int r = 0; r < 4; ++r) od[r * 68] = pv[r];
    }
    __syncthreads();

    // coalesced store + residual: thread -> och = tid>>2, 8 q from (tid&3)*8
    const float gamma = gamma_p[0];
    const int soch = tid >> 2;
    const int qoff = (tid & 3) * 8;
    const float* xrow = x   + (size_t)n * CCH * LL + (size_t)soch * LL + l0 + qoff;
    float*       orow = out + (size_t)n * CCH * LL + (size_t)soch * LL + l0 + qoff;
#pragma unroll
    for (int i = 0; i < 2; ++i) {
        float4 xv = *(const float4*)(xrow + i * 4);
        float4 ov;
        ov.x = xv.x + gamma * out_s[(qoff + i * 4)     * 68 + soch];
        ov.y = xv.y + gamma * out_s[(qoff + i * 4 + 1) * 68 + soch];
        ov.z = xv.z + gamma * out_s[(qoff + i * 4 + 2) * 68 + soch];
        ov.w = xv.w + gamma * out_s[(qoff + i * 4 + 3) * 68 + soch];
        *(float4*)(orow + i * 4) = ov;
    }
}

// ---------------------------------------------------------------------------
extern "C" void kernel_launch(void* const* d_in, const int* in_sizes, int n_in,
                              void* d_out, int out_size, void* d_ws, size_t ws_size,
                              hipStream_t stream) {
    const float* x       = (const float*)d_in[0];
    const float* w_theta = (const float*)d_in[1];
    const float* w_phi   = (const float*)d_in[2];
    const float* w_g     = (const float*)d_in[3];
    const float* w_o     = (const float*)d_in[4];
    const float* gamma   = (const float*)d_in[5];
    float* out = (float*)d_out;

    // ws layout (f16): theta 1 MB | phi 256 KB | gT 1 MB
    _Float16* theta_h = (_Float16*)d_ws;                    // N*L*8
    _Float16* phi_h   = theta_h + (size_t)NB * LL * 8;      // N*D*8
    _Float16* gT_h    = phi_h   + (size_t)NB * DD * 8;      // N*32*D

    prep_kernel<<<1024, 256, 0, stream>>>(x, w_theta, w_phi, w_g,
                                          theta_h, phi_h, gT_h);
    attn_kernel<<<2048, 256, 0, stream>>>(x, theta_h, phi_h, gT_h,
                                          w_o, gamma, out);
}